// Round 6
// baseline (102.147 us; speedup 1.0000x reference)
//
#include <hip/hip_runtime.h>
#include <hip/hip_bf16.h>
#include <math.h>

// InfiniteContextAttention — causal mask reaches only keys 0..15 (= compressed_k/v[:,:, :16]).
// Pipeline: q = hidden @ Wq^T -> 16-key causal attention -> out = attn @ Wo^T.
//
// GEMM v6 = v3 structure (proven 37.4us) + pipeline fixes:
//  - 512 blocks x 256 thr; block = 64 cols x K-slice 512; A staged once in
//    XOR-swizzled bf16 LDS (ds_read/lgkmcnt), W streamed global->reg (vmcnt) —
//    the two streams stay in separate wait queues (v5 lesson: mixing them
//    head-of-line blocks L2 A-loads behind HBM W-loads).
//  - depth-3 W prefetch (6 float4 in flight/lane), prologue issued BEFORE staging.
//  - v_cvt_pk_bf16_f32 conversions (m240), 16B staging granules.
//  - gemm2 fuses the slice-reduce: per-column-group atomic ticket, last block
//    sums the 8 slices in fixed order (bit-deterministic) -> no 4th kernel.

#define HID 4096
#define NROW 32
#define NSLICE 8
#define KSL 512
#define NSTEP 16                  // KSL / 32
#define PART_STRIDE (NROW * HID)  // 131072 floats per slice

typedef __attribute__((ext_vector_type(8))) short short8;
typedef __attribute__((ext_vector_type(4))) float f32x4;

__device__ __forceinline__ short8 cvt8(float4 a, float4 b) {
    union { short8 s; __hip_bfloat162 h[4]; } u;
    u.h[0] = __float22bfloat162_rn(make_float2(a.x, a.y));
    u.h[1] = __float22bfloat162_rn(make_float2(a.z, a.w));
    u.h[2] = __float22bfloat162_rn(make_float2(b.x, b.y));
    u.h[3] = __float22bfloat162_rn(make_float2(b.z, b.w));
    return u.s;
}

template<bool AF32, bool FINAL>
__global__ __launch_bounds__(256, 2)
void gemm_mfma(const void* __restrict__ Ain,   // [32][4096] fp32 (AF32) or bf16
               const float* __restrict__ W,    // [4096][4096] fp32
               float* __restrict__ P,          // [8][32][4096] fp32 partials
               float* __restrict__ Cout,       // [32][4096] final (FINAL only)
               int* __restrict__ tickets)      // [64]; reset here when !FINAL
{
    __shared__ short As[NROW * KSL];  // 32 KB bf16, XOR-swizzled
    const int tid  = threadIdx.x;
    const int lane = tid & 63;
    const int wv   = tid >> 6;            // wave 0..3 -> 16-col tile
    const int cg   = blockIdx.x & 63;     // column group (64 cols)
    const int sl   = blockIdx.x >> 6;     // K-slice 0..7
    const int ks   = sl * KSL;

    if (!FINAL && blockIdx.x < 64 && tid == 0) tickets[blockIdx.x] = 0;

    const int l15 = lane & 15, lq = lane >> 4;
    const int jcol = cg * 64 + wv * 16 + l15;
    const float* wp = W + (size_t)jcol * HID + ks + lq * 8;

    // ---- W prologue (depth-3) issued FIRST so HBM never idles during staging ----
    float4 w0a = *(const float4*)(wp);
    float4 w0b = *(const float4*)(wp + 4);
    float4 w1a = *(const float4*)(wp + 32);
    float4 w1b = *(const float4*)(wp + 36);
    float4 w2a = *(const float4*)(wp + 64);
    float4 w2b = *(const float4*)(wp + 68);

    // ---- stage A slice -> LDS (16B granules, XOR bits 4-6 by row&7) ----
    {
        const int r  = tid >> 3;          // row 0..31
        const int c8 = tid & 7;           // granule subgroup within row
        const int rx = (r & 7) << 4;
        char* lb = (char*)As + r * (KSL * 2);   // 1024 B per row
        if (AF32) {
            const float* src = (const float*)Ain + (size_t)r * HID + ks + c8 * 8;
#pragma unroll
            for (int i = 0; i < 8; ++i) {
                float4 v0 = *(const float4*)(src + i * 64);
                float4 v1 = *(const float4*)(src + i * 64 + 4);
                int byte = ((c8 + 8 * i) * 16) ^ rx;
                *(short8*)(lb + byte) = cvt8(v0, v1);
            }
        } else {
            const short* src = (const short*)Ain + (size_t)r * HID + ks + c8 * 8;
#pragma unroll
            for (int i = 0; i < 8; ++i) {
                short8 v = *(const short8*)(src + i * 64);
                int byte = ((c8 + 8 * i) * 16) ^ rx;
                *(short8*)(lb + byte) = v;
            }
        }
    }
    __syncthreads();  // the only barrier

    const char* lA0 = (const char*)As + l15 * (KSL * 2);
    const char* lA1 = lA0 + 16 * (KSL * 2);
    const int rswz = (l15 & 7) << 4;

    f32x4 acc0 = {0.f, 0.f, 0.f, 0.f}, acc1 = {0.f, 0.f, 0.f, 0.f};

#pragma unroll
    for (int kk = 0; kk < NSTEP; ++kk) {
        float4 nA = {}, nB = {};
        if (kk < NSTEP - 3) {   // depth-3 rolling prefetch
            nA = *(const float4*)(wp + (kk + 3) * 32);
            nB = *(const float4*)(wp + (kk + 3) * 32 + 4);
        }
        const int byte = ((kk * 64) + (lq * 16)) ^ rswz;
        short8 a0 = *(const short8*)(lA0 + byte);
        short8 a1 = *(const short8*)(lA1 + byte);
        short8 b = cvt8(w0a, w0b);
        acc0 = __builtin_amdgcn_mfma_f32_16x16x32_bf16(a0, b, acc0, 0, 0, 0);
        acc1 = __builtin_amdgcn_mfma_f32_16x16x32_bf16(a1, b, acc1, 0, 0, 0);
        w0a = w1a; w0b = w1b; w1a = w2a; w1b = w2b; w2a = nA; w2b = nB;
    }

    // ---- partial store: C/D layout col=lane&15, row=(lane>>4)*4+reg (m89) ----
    float* pout = P + (size_t)sl * PART_STRIDE + jcol;
#pragma unroll
    for (int rr = 0; rr < 4; ++rr) {
        pout[(size_t)(lq * 4 + rr) * HID]      = acc0[rr];
        pout[(size_t)(16 + lq * 4 + rr) * HID] = acc1[rr];
    }

    if (FINAL) {
        // ---- deterministic fan-in: last slice-block of this cg reduces ----
        __threadfence();                       // release: partials -> device scope
        __shared__ int winS;
        __syncthreads();                       // all threads' stores fenced
        if (tid == 0) {
            int old = atomicAdd(&tickets[cg], 1);   // device-scope (G12)
            winS = (old == NSLICE - 1);
        }
        __syncthreads();
        if (!winS) return;
        __threadfence();                       // acquire: see all 8 slices

        const int j   = cg * 64 + (tid & 63);
        const int rr0 = tid >> 6;
#pragma unroll
        for (int rr = rr0; rr < NROW; rr += 4) {
            float s = 0.f;
#pragma unroll
            for (int t = 0; t < NSLICE; ++t)   // fixed order -> bit-deterministic
                s += P[(size_t)t * PART_STRIDE + (size_t)rr * HID + j];
            Cout[(size_t)rr * HID + j] = s;
        }
    }
}

// One wave per (b,h,i): fuses 8-slice q-reduction with 16-key causal attention.
// Output bf16 (feeds gemm2's A directly).
__global__ __launch_bounds__(256)
void attn16_kernel(const float* __restrict__ P,   // q partials [8][32][4096]
                   const float* __restrict__ ck,
                   const float* __restrict__ cv,
                   __hip_bfloat16* __restrict__ o) // [32][4096] bf16
{
    const int lane = threadIdx.x & 63;
    const int g = blockIdx.x * 4 + (threadIdx.x >> 6);  // 0..1023
    const int b = g >> 9;
    const int h = (g >> 4) & 31;
    const int i = g & 15;

    const size_t qoff = ((size_t)(b * 16 + i)) * HID + h * 128 + 2 * lane;
    float2 q2 = {0.f, 0.f};
#pragma unroll
    for (int s = 0; s < NSLICE; ++s) {
        float2 p = *(const float2*)(P + (size_t)s * PART_STRIDE + qoff);
        q2.x += p.x; q2.y += p.y;
    }
    const size_t kvoff = ((size_t)(b * 32 + h)) * 2048 * 128 + 2 * lane;
    const float* kp = ck + kvoff;
    const float* vp = cv + kvoff;

    float e[16];
#pragma unroll
    for (int s = 0; s < 16; ++s) {
        float2 k2 = *(const float2*)(kp + (size_t)s * 128);
        float p = q2.x * k2.x + q2.y * k2.y;
#pragma unroll
        for (int m = 32; m >= 1; m >>= 1) p += __shfl_xor(p, m, 64);
        e[s] = (s <= i) ? p * 0.08838834764831845f : -3.4e38f;  // i wave-uniform
    }
    float mx = e[0];
#pragma unroll
    for (int s = 1; s < 16; ++s) mx = fmaxf(mx, e[s]);
    float den = 0.f;
#pragma unroll
    for (int s = 0; s < 16; ++s) { e[s] = __expf(e[s] - mx); den += e[s]; }
    const float inv = 1.0f / den;

    float ox = 0.f, oy = 0.f;
#pragma unroll
    for (int s = 0; s < 16; ++s) {
        float2 v2 = *(const float2*)(vp + (size_t)s * 128);
        ox += e[s] * v2.x;
        oy += e[s] * v2.y;
    }
    __hip_bfloat162 r2 = __float22bfloat162_rn(make_float2(ox * inv, oy * inv));
    *(__hip_bfloat162*)(o + qoff) = r2;
}

extern "C" void kernel_launch(void* const* d_in, const int* in_sizes, int n_in,
                              void* d_out, int out_size, void* d_ws, size_t ws_size,
                              hipStream_t stream) {
    const float* hidden = (const float*)d_in[0];  // [2][16][4096]
    const float* ck     = (const float*)d_in[3];  // [2][32][2048][128]
    const float* cv     = (const float*)d_in[4];
    const float* Wq     = (const float*)d_in[5];  // [4096][4096]
    const float* Wo     = (const float*)d_in[8];
    float* out = (float*)d_out;                   // [2][16][4096]

    char* ws = (char*)d_ws;
    float*          P       = (float*)ws;                        // 4 MB partials
    __hip_bfloat16* abf     = (__hip_bfloat16*)(ws + (4u << 20));// 256 KB
    int*            tickets = (int*)(ws + (4u << 20) + (256u << 10)); // 256 B

    hipLaunchKernelGGL((gemm_mfma<true,  false>), dim3(512), dim3(256), 0, stream,
                       (const void*)hidden, Wq, P, (float*)nullptr, tickets);
    hipLaunchKernelGGL(attn16_kernel,             dim3(256), dim3(256), 0, stream,
                       P, ck, cv, abf);
    hipLaunchKernelGGL((gemm_mfma<false, true>),  dim3(512), dim3(256), 0, stream,
                       (const void*)abf, Wo, P, out, tickets);
}

// Round 7
// 37.435 us; speedup vs baseline: 2.7287x; 2.7287x over previous
//
#include <hip/hip_runtime.h>
#include <math.h>

// InfiniteContextAttention — causal mask reaches only keys 0..15 (= compressed_k/v[:,:, :16]).
// Pipeline: q = hidden @ Wq^T -> 16-key causal attention -> out = attn @ Wo^T.
//
// v7 = v3 (proven 37.4us) with EXACTLY ONE change: W prefetch depth 1 -> 3
// (rolling, initialized after the staging barrier, v3's original position).
// Rationale: 64MB W / 256 CU = 10.9us HBM floor; v3 gemm ~14-15us; gap =
// latency bubbles at depth-1 (2 float4/lane in flight, 2 waves/SIMD).

#define HID 4096
#define NROW 32
#define NSLICE 8
#define KSL 512
#define NSTEP 16
#define PART_STRIDE (NROW * HID)  // 131072 floats per slice

typedef __attribute__((ext_vector_type(8))) short short8;
typedef __attribute__((ext_vector_type(4))) float f32x4;

__device__ __forceinline__ unsigned short bf16_rne(float x) {
    union { float f; unsigned u; } c; c.f = x;
    unsigned u = c.u;
    return (unsigned short)((u + 0x7fffu + ((u >> 16) & 1u)) >> 16);
}

__global__ __launch_bounds__(256, 2)
void gemm_mfma(const float* __restrict__ A,   // [32][4096] fp32
               const float* __restrict__ W,   // [4096][4096] fp32
               float* __restrict__ P)         // [8][32][4096] fp32 partials
{
    __shared__ short As[NROW * KSL];  // 32 KB bf16, XOR-swizzled (T2)
    const int tid  = threadIdx.x;
    const int lane = tid & 63;
    const int wv   = tid >> 6;            // wave 0..3 -> 16-col tile
    const int cg   = blockIdx.x & 63;     // column group (64 cols)
    const int sl   = blockIdx.x >> 6;     // K-slice 0..7
    const int ks   = sl * KSL;

    // ---- stage A slice (fp32 -> bf16, swizzled), coalesced 128B-granule reads ----
    {
        const int r  = tid >> 3;          // row 0..31
        const int c8 = tid & 7;           // float4 column subgroup
        const float* src = A + (size_t)r * HID + ks + c8 * 4;
        char* lb = (char*)As + r * (KSL * 2);
        const int rx = (r & 7) << 4;
#pragma unroll
        for (int i = 0; i < 16; ++i) {
            float4 v = *(const float4*)(src + i * 32);
            unsigned long long pk =
                  (unsigned long long)bf16_rne(v.x)
                | ((unsigned long long)bf16_rne(v.y) << 16)
                | ((unsigned long long)bf16_rne(v.z) << 32)
                | ((unsigned long long)bf16_rne(v.w) << 48);
            int byte = ((c8 + 8 * i) * 8) ^ rx;
            *(unsigned long long*)(lb + byte) = pk;
        }
    }
    __syncthreads();  // the only barrier: LDS written once

    const int l15 = lane & 15, lq = lane >> 4, l7 = lane & 7;
    const int jcol = cg * 64 + wv * 16 + l15;
    const float* wp = W + (size_t)jcol * HID + ks + lq * 8;
    const char* lA0 = (const char*)As + l15 * (KSL * 2);
    const char* lA1 = (const char*)As + (16 + l15) * (KSL * 2);
    const int rswz = l7 << 4;

    f32x4 acc0 = {0.f, 0.f, 0.f, 0.f}, acc1 = {0.f, 0.f, 0.f, 0.f};

    // ---- ONLY CHANGE vs v3: depth-3 rolling W prefetch (was depth-1) ----
    float4 w0a = *(const float4*)(wp);
    float4 w0b = *(const float4*)(wp + 4);
    float4 w1a = *(const float4*)(wp + 32);
    float4 w1b = *(const float4*)(wp + 36);
    float4 w2a = *(const float4*)(wp + 64);
    float4 w2b = *(const float4*)(wp + 68);

#pragma unroll
    for (int kk = 0; kk < NSTEP; ++kk) {
        float4 nA = {}, nB = {};
        if (kk < NSTEP - 3) {
            nA = *(const float4*)(wp + (kk + 3) * 32);
            nB = *(const float4*)(wp + (kk + 3) * 32 + 4);
        }
        const int byte = ((kk * 64) + (lq * 16)) ^ rswz;
        short8 a0 = *(const short8*)(lA0 + byte);
        short8 a1 = *(const short8*)(lA1 + byte);
        short8 b;
        b[0] = (short)bf16_rne(w0a.x); b[1] = (short)bf16_rne(w0a.y);
        b[2] = (short)bf16_rne(w0a.z); b[3] = (short)bf16_rne(w0a.w);
        b[4] = (short)bf16_rne(w0b.x); b[5] = (short)bf16_rne(w0b.y);
        b[6] = (short)bf16_rne(w0b.z); b[7] = (short)bf16_rne(w0b.w);
        acc0 = __builtin_amdgcn_mfma_f32_16x16x32_bf16(a0, b, acc0, 0, 0, 0);
        acc1 = __builtin_amdgcn_mfma_f32_16x16x32_bf16(a1, b, acc1, 0, 0, 0);
        w0a = w1a; w0b = w1b; w1a = w2a; w1b = w2b; w2a = nA; w2b = nB;
    }

    // ---- epilogue: C/D layout col=lane&15, row=(lane>>4)*4+reg (m89-verified) ----
    float* pout = P + (size_t)sl * PART_STRIDE + jcol;
#pragma unroll
    for (int rr = 0; rr < 4; ++rr) {
        pout[(size_t)(lq * 4 + rr) * HID]        = acc0[rr];
        pout[(size_t)(16 + lq * 4 + rr) * HID]   = acc1[rr];
    }
}

// One wave per (b,h,i): fuses the 8-slice q-reduction with 16-key causal attention.
__global__ __launch_bounds__(256)
void attn16_kernel(const float* __restrict__ P,   // q partials [8][32][4096]
                   const float* __restrict__ ck,
                   const float* __restrict__ cv,
                   float* __restrict__ o)          // [32][4096]
{
    const int lane = threadIdx.x & 63;
    const int g = blockIdx.x * 4 + (threadIdx.x >> 6);  // 0..1023
    const int b = g >> 9;
    const int h = (g >> 4) & 31;
    const int i = g & 15;

    const size_t qoff = ((size_t)(b * 16 + i)) * HID + h * 128 + 2 * lane;
    float2 q2 = {0.f, 0.f};
#pragma unroll
    for (int s = 0; s < NSLICE; ++s) {
        float2 p = *(const float2*)(P + (size_t)s * PART_STRIDE + qoff);
        q2.x += p.x; q2.y += p.y;
    }
    const size_t kvoff = ((size_t)(b * 32 + h)) * 2048 * 128 + 2 * lane;
    const float* kp = ck + kvoff;
    const float* vp = cv + kvoff;

    float e[16];
#pragma unroll
    for (int s = 0; s < 16; ++s) {
        float2 k2 = *(const float2*)(kp + (size_t)s * 128);
        float p = q2.x * k2.x + q2.y * k2.y;
#pragma unroll
        for (int m = 32; m >= 1; m >>= 1) p += __shfl_xor(p, m, 64);
        e[s] = (s <= i) ? p * 0.08838834764831845f : -3.4e38f;  // i wave-uniform
    }
    float mx = e[0];
#pragma unroll
    for (int s = 1; s < 16; ++s) mx = fmaxf(mx, e[s]);
    float den = 0.f;
#pragma unroll
    for (int s = 0; s < 16; ++s) { e[s] = __expf(e[s] - mx); den += e[s]; }
    const float inv = 1.0f / den;

    float ox = 0.f, oy = 0.f;
#pragma unroll
    for (int s = 0; s < 16; ++s) {
        float2 v2 = *(const float2*)(vp + (size_t)s * 128);
        ox += e[s] * v2.x;
        oy += e[s] * v2.y;
    }
    float2 res; res.x = ox * inv; res.y = oy * inv;
    *(float2*)(o + qoff) = res;
}

// out[i] = sum over 8 slices of P[s][i]; 32768 float4s.
__global__ __launch_bounds__(256)
void reduce8_kernel(const float* __restrict__ P, float* __restrict__ out)
{
    const int idx = blockIdx.x * 256 + threadIdx.x;  // float4 index
    const float4* p4 = (const float4*)P;
    float4 s = p4[idx];
#pragma unroll
    for (int t = 1; t < NSLICE; ++t) {
        float4 v = p4[idx + t * (PART_STRIDE / 4)];
        s.x += v.x; s.y += v.y; s.z += v.z; s.w += v.w;
    }
    ((float4*)out)[idx] = s;
}

extern "C" void kernel_launch(void* const* d_in, const int* in_sizes, int n_in,
                              void* d_out, int out_size, void* d_ws, size_t ws_size,
                              hipStream_t stream) {
    const float* hidden = (const float*)d_in[0];  // [2][16][4096]
    const float* ck     = (const float*)d_in[3];  // [2][32][2048][128]
    const float* cv     = (const float*)d_in[4];
    const float* Wq     = (const float*)d_in[5];  // [4096][4096]
    const float* Wo     = (const float*)d_in[8];
    float* out  = (float*)d_out;                  // [2][16][4096]
    float* part = (float*)d_ws;                   // [8][32][4096] = 4 MB
    float* abuf = part + NSLICE * PART_STRIDE;    // [32][4096] attn output

    hipLaunchKernelGGL(gemm_mfma,     dim3(512), dim3(256), 0, stream, hidden, Wq, part);
    hipLaunchKernelGGL(attn16_kernel, dim3(256), dim3(256), 0, stream, part, ck, cv, abuf);
    hipLaunchKernelGGL(gemm_mfma,     dim3(512), dim3(256), 0, stream, abuf, Wo, part);
    hipLaunchKernelGGL(reduce8_kernel,dim3(128), dim3(256), 0, stream, part, out);
}